// Round 6
// baseline (162.093 us; speedup 1.0000x reference)
//
#include <hip/hip_runtime.h>

// ---------------------------------------------------------------------------
// HybridLossDynamic: total = mse + ssim_loss + 0.7*gme over (2,1,128,128,128)
// fp32 volumes. Outputs: [total, mse, ssim_loss, gme].
//
// r20, on top of r19 (149.4 us):
//   * X+Y BLUR FUSED via rolling ring: per block (one z-slice, half-y),
//     5 chunks of {stage 16 rows (s,d fp32, MSE inline) -> x-blur into a
//     32-slot ring of h4 rows -> y-emit 16 output rows}. Eliminates the
//     A-read + B-write round trip (-64 MB HBM) and one launch.
//     LDS 50.4KB -> 3 blocks/CU = same occupancy fa already ran at (38%,
//     r19 measured), 15 barriers/block. This is NOT r10/r11's failed
//     tile fusion (63KB, whole-tile) nor r12's thin slabs.
//   * Pipeline: L1 = xyblur || sobel (512+1024, bid%3: 0=xy, 1/2=sobel);
//     L2 = zblur+ssim || edge (unchanged r19, reads xy-blurred field);
//     final. 4 dispatches.
//
// SSIM chain: 4 fields {s,d,ss,dd}, s=p+t, d=p-t (r15, exact algebra).
// Interleaved [voxel][4 fields] layout (r18).
//
// Measured lessons pinned (DO NOT REVISIT):
//   r7:  y+z fusion -> scattered 16B staging, 200MB HBM. REGRESSED
//   r9/r16: IN-KERNEL FINAL FOLD (threadfence+counter) COSTS >100us.
//   r10/r11: x+y WHOLE-TILE fusion, 63KB/2 blocks/CU. REGRESSED
//   r12: thin per-field slabs -> 5x barrier-latency exposure. REGRESSED
//   r15/r17: SQ_LDS_BANK_CONFLICT = benign 2-way aliasing. Not the lever.
//   r17: sobel 16-slice split: +5MB halo, no gain. 32 slices/block.
//   r19: fa is NOT barrier-bound; wblur restructure + occupancy change
//     moved nothing. fa's 2.5 TB/s is traffic-pattern-inherent.
//
// ws: AB [0,32) MiB (xy-blurred) | acc @80 MiB | gm @84 MiB (16 MiB).
// ---------------------------------------------------------------------------

#define VOL 4194304        // 2*128^3 (both batch images)
#define HV  2097152        // one batch image, 128^3

typedef _Float16 h2 __attribute__((ext_vector_type(2)));
typedef _Float16 h4 __attribute__((ext_vector_type(4)));
typedef _Float16 h8 __attribute__((ext_vector_type(8)));

// 11-tap Gaussian, sigma=1.5, normalized:
constexpr float GW[11] = {
    0.00102838f, 0.00759876f, 0.03600077f, 0.10936070f, 0.21300554f,
    0.26601173f,
    0.21300554f, 0.10936070f, 0.03600077f, 0.00759876f, 0.00102838f};

// Accumulator region layout (all zero-initialized by one memset):
//   dbl[0..511] mse bins | dbl[512..1023] ssim bins | dbl[1024..1535] abs bins
//   ui[0..1023]  ~min v0 (COMPLEMENTED bits, atomicMax) | ui[1024..2047] ~min
//   v1 | ui[2048..3071] max v0 | ui[3072..4095] max v1

// ---- role: fused X+Y blur for one z-slice, half y-range --------------------
// Ring invariant at chunk c0 (after x-blur): rows c0-16..c0+15 live in
// slots (row&31); emit window [c0-5, c0+10] reads rows c0-10..c0+15. Next
// chunk's x-blur overwrites slots of rows c0-16..c0-1, hence barrier after
// emit. Chunk starts: ybase-5 + 16j, j=0..4 -> stages rows ybase-5..ybase+74
// (each exactly once; out-of-[0,128) rows zero-padded, matching 'SAME').
__device__ __forceinline__ void xyblur_body(
    const float* __restrict__ p, const float* __restrict__ t,
    _Float16* __restrict__ A, double* __restrict__ mseB, const int xyidx,
    char* __restrict__ pool, float* __restrict__ redw) {
  float (* __restrict__ sr)[138] = (float (*)[138])pool;            // 8832 B
  float (* __restrict__ dr)[138] = (float (*)[138])(pool + 8832);   // 8832 B
  h4 (* __restrict__ ring)[128]  = (h4 (*)[128])(pool + 17664);     // 32768 B
  const int tid = threadIdx.x;
  const int yhalf = xyidx & 1;
  const int z = (xyidx >> 1) & 127;
  const int b = xyidx >> 8;
  const int ybase = yhalf << 6;
  const int sbase = (b << 21) + (z << 14);   // voxel idx of (b,z,0,0)
  h4* __restrict__ A4 = (h4*)A;
  if (tid < 160) {                           // zero the 10 pad cols per row
    const int r = tid / 10, j = tid % 10;
    const int c = (j < 5) ? j : (128 + j);   // {0..4, 133..137}
    sr[r][c] = 0.f; dr[r][c] = 0.f;
  }
  float msel = 0.f;
  for (int j = 0; j < 5; ++j) {
    const int c0 = ybase - 5 + (j << 4);
    // ---- stage 16 rows (zero-pad outside volume), MSE on own half ----
#pragma unroll
    for (int i = 0; i < 8; ++i) {
      const int v = (i << 8) + tid;
      const int rr = v >> 7, x = v & 127;
      const int gy = c0 + rr;
      float sv = 0.f, dv = 0.f;
      if ((unsigned)gy < 128u) {
        const float pv = p[sbase + (gy << 7) + x];
        const float tv = t[sbase + (gy << 7) + x];
        sv = pv + tv; dv = pv - tv;
        if (gy >= ybase && gy <= ybase + 63) msel += dv * dv;
      }
      sr[rr][5 + x] = sv;
      dr[rr][5 + x] = dv;
    }
    __syncthreads();
    // ---- x-blur 16 rows into ring ----
#pragma unroll
    for (int i = 0; i < 8; ++i) {
      const int v = (i << 8) + tid;
      const int rr = v >> 7, x = v & 127;
      float as = 0.f, ad = 0.f, ass = 0.f, add_ = 0.f;
#pragma unroll
      for (int k = 0; k < 11; ++k) {
        const float w = GW[k];
        const float a = sr[rr][x + k];
        const float bb = dr[rr][x + k];
        const float wa = w * a;
        const float wb = w * bb;
        as += wa; ad += wb;
        ass += wa * a; add_ += wb * bb;
      }
      h4 o;
      o[0] = (_Float16)as;  o[1] = (_Float16)ad;
      o[2] = (_Float16)ass; o[3] = (_Float16)add_;
      ring[(c0 + rr) & 31][x] = o;
    }
    __syncthreads();
    // ---- y-emit window [c0-5, c0+10] clipped to this half ----
#pragma unroll
    for (int i = 0; i < 8; ++i) {
      const int v = (i << 8) + tid;
      const int er = c0 - 5 + (v >> 7);
      const int x = v & 127;
      if (er >= ybase && er <= ybase + 63) {
        h4 acc{};
#pragma unroll
        for (int k = 0; k < 11; ++k) {
          const _Float16 w = (_Float16)GW[k];
          acc += w * ring[(er - 5 + k) & 31][x];   // v_pk_fma_f16 x2
        }
        A4[sbase + (er << 7) + x] = acc;           // 8B/lane single stream
      }
    }
    __syncthreads();
  }
  redw[tid] = msel;
  __syncthreads();
  for (int s = 128; s > 0; s >>= 1) {
    if (tid < s) redw[tid] += redw[tid + s];
    __syncthreads();
  }
  if (tid == 0) atomicAdd(&mseB[(xyidx & 63) << 3], (double)redw[0]);
}

// ---- role: Sobel via separable s/d/u decomposition, z-streamed (32/block) --
// LDS: 3 slices, row stride 24 (18 valid cols), from pool.
__device__ __forceinline__ void sobel_body(
    const float* __restrict__ p, const float* __restrict__ t,
    _Float16* __restrict__ gmP, _Float16* __restrict__ gmT,
    unsigned int* __restrict__ ui, const int bx, const int by, const int bz,
    char* __restrict__ pool, float* __restrict__ rmin) {
  float* __restrict__ sb   = (float*)pool;           // 1296*4 = 5184 B
  float* __restrict__ rmax = (float*)(pool + 5184);  // 1024 B
  const int tid = threadIdx.x;
  const int tx = tid & 15;
  const int ty = tid >> 4;
  const int x0 = bx << 4;
  const int y0 = by << 4;
  const int vol = bz >> 3;
  const int b   = (bz >> 2) & 1;
  const int z0  = (bz & 3) << 5;             // 32-slice chunks
  const float* __restrict__ img = vol ? t : p;
  _Float16* __restrict__ gm = vol ? gmT : gmP;
  const int vb = b << 21;

  // staging slots: pass1 = tid, pass2 = tid+256 (rows 0..17, stride 24)
  const int ly1 = tid / 24, lx1 = tid % 24;
  const bool v1 = (lx1 < 18);
  int gy1 = y0 - 1 + ly1; gy1 = gy1 < 0 ? 1 : (gy1 > 127 ? 126 : gy1);
  int gx1 = x0 - 1 + lx1; gx1 = gx1 < 0 ? 1 : (gx1 > 127 ? 126 : gx1);
  const int off1 = (gy1 << 7) + gx1;
  const int s2i = tid + 256;
  const int ly2 = s2i / 24, lx2 = s2i % 24;
  const bool v2 = (s2i < 432) && (lx2 < 18);
  int gy2 = y0 - 1 + ly2; gy2 = gy2 < 0 ? 1 : (gy2 > 127 ? 126 : gy2);
  int gx2 = x0 - 1 + lx2; gx2 = gx2 < 0 ? 1 : (gx2 > 127 ? 126 : gx2);
  const int off2 = (gy2 << 7) + gx2;
  const int rb = ty * 24 + tx;
  const int gbase = vb + (z0 << 14) + ((y0 + ty) << 7) + (x0 + tx);

  float Y0[7], Y1[7], Y2[7];
  float rv1 = 0.f, rv2 = 0.f;
  float lmin = 3.4e38f, lmax = 0.f;

#define LOADR(ZS) {                                                         \
    const int zc_ = (ZS) > 127 ? 126 : (ZS);                                \
    const int za_ = vb + (zc_ << 14);                                       \
    if (v1) rv1 = img[za_ + off1];                                          \
    if (v2) rv2 = img[za_ + off2]; }

#define WRITELDS(BOFF) {                                                    \
    if (v1) sb[(BOFF) + tid] = rv1;                                         \
    if (v2) sb[(BOFF) + s2i] = rv2; }

#define COMPY(P) {                                                          \
    const int o_ = (P) * 432 + rb;                                          \
    const float r00 = sb[o_],      r01 = sb[o_ + 1],  r02 = sb[o_ + 2];     \
    const float r10 = sb[o_ + 24], r11 = sb[o_ + 25], r12 = sb[o_ + 26];    \
    const float r20 = sb[o_ + 48], r21 = sb[o_ + 49], r22 = sb[o_ + 50];    \
    const float dx0 = r02 - r00, dx1 = r12 - r10, dx2 = r22 - r20;          \
    const float ux0 = r00 + r01 + r02, ux1 = r10 + r11 + r12,               \
                ux2 = r20 + r21 + r22;                                      \
    const float sx0 = ux0 + r01, sx1 = ux1 + r11, sx2 = ux2 + r21;          \
    Y##P[1] = dx0 + dx1 + dx2;           /* uydx */                         \
    Y##P[0] = Y##P[1] + dx1;             /* sydx */                         \
    Y##P[2] = sx2 - sx0;                 /* dysx */                         \
    Y##P[4] = sx0 + sx1 + sx2;           /* uysx */                         \
    Y##P[3] = Y##P[4] + sx1;             /* sysx */                         \
    Y##P[5] = ux2 - ux0;                 /* dyux */                         \
    Y##P[6] = (ux0 + ux2) + 2.f * ux1; } /* syux */

#define EMIT(I, P0, P1, P2) {                                               \
    const float E_ = Y##P0[0] + Y##P1[0] + Y##P2[0];                        \
    const float g1 = E_ + Y##P1[0];                                         \
    const float tA = Y##P0[1] + Y##P1[1] + Y##P2[1];                        \
    const float A_ = tA + Y##P1[1];                                         \
    const float D_ = Y##P0[2] + Y##P1[2] + Y##P2[2];                        \
    const float g2 = D_ + Y##P1[2];                                         \
    const float g3 = Y##P2[3] - Y##P0[3];                                   \
    const float C_ = Y##P2[4] - Y##P0[4];                                   \
    const float B_ = (Y##P0[5] + Y##P2[5]) + 2.f * Y##P1[5];                \
    const float F_ = Y##P2[6] - Y##P0[6];                                   \
    const float g4 = A_ - B_, g5 = A_ + B_;                                 \
    const float g6 = C_ - D_, g7 = C_ + D_;                                 \
    const float g8 = E_ - F_, g9 = E_ + F_;                                 \
    float ss_ = 9e-6f, t_;                                                  \
    t_ = g1 + 1e-6f; ss_ = fmaf(t_, t_, ss_);                               \
    t_ = g2 + 1e-6f; ss_ = fmaf(t_, t_, ss_);                               \
    t_ = g3 + 1e-6f; ss_ = fmaf(t_, t_, ss_);                               \
    t_ = g4 + 1e-6f; ss_ = fmaf(t_, t_, ss_);                               \
    t_ = g5 + 1e-6f; ss_ = fmaf(t_, t_, ss_);                               \
    t_ = g6 + 1e-6f; ss_ = fmaf(t_, t_, ss_);                               \
    t_ = g7 + 1e-6f; ss_ = fmaf(t_, t_, ss_);                               \
    t_ = g8 + 1e-6f; ss_ = fmaf(t_, t_, ss_);                               \
    t_ = g9 + 1e-6f; ss_ = fmaf(t_, t_, ss_);                               \
    const _Float16 gh = (_Float16)sqrtf(ss_);                               \
    gm[gbase + ((I) << 14)] = gh;                                           \
    const float gq = (float)gh;                                             \
    lmin = fminf(lmin, gq); lmax = fmaxf(lmax, gq); }

#define BODY(I, P0, P1, P2) {                                               \
    WRITELDS((P2) * 432);                                                   \
    LOADR(z0 + (I) + 2);                                                    \
    __syncthreads();                                                        \
    COMPY(P2);                                                              \
    EMIT(I, P0, P1, P2); }

  {
    const int zp = (z0 == 0) ? 1 : (z0 - 1);
    LOADR(zp);  WRITELDS(0);
    LOADR(z0);  WRITELDS(432);
    __syncthreads();
    COMPY(0);
    COMPY(1);
    LOADR(z0 + 1);                           // prime the pipeline
  }
  for (int ii = 0; ii < 30; ii += 3) {
    BODY(ii,     0, 1, 2);
    BODY(ii + 1, 1, 2, 0);
    BODY(ii + 2, 2, 0, 1);
  }
  BODY(30, 0, 1, 2);
  BODY(31, 1, 2, 0);

#undef BODY
#undef EMIT
#undef COMPY
#undef WRITELDS
#undef LOADR

  rmin[tid] = lmin; rmax[tid] = lmax;
  __syncthreads();
  for (int st = 128; st > 0; st >>= 1) {
    if (tid < st) {
      rmin[tid] = fminf(rmin[tid], rmin[tid + st]);
      rmax[tid] = fmaxf(rmax[tid], rmax[tid + st]);
    }
    __syncthreads();
  }
  if (tid == 0) {
    const int bin = (bx + (by << 3) + (bz << 6)) & 63;
    // min stored as max of complemented bits (positive floats bit-ordered):
    atomicMax(&ui[vol * 1024 + (bin << 4)], ~__float_as_uint(rmin[0]));
    atomicMax(&ui[2048 + vol * 1024 + (bin << 4)], __float_as_uint(rmax[0]));
  }
}

// ---- role: mean |norm_p - norm_t| (h8 loads) -------------------------------
__device__ __forceinline__ void edge_body(
    const _Float16* __restrict__ gmP, const _Float16* __restrict__ gmT,
    const unsigned int* __restrict__ ui, double* __restrict__ absB,
    const int bidx, float* __restrict__ rede) {
  unsigned umnp = 0u, umnt = 0u, umxp = 0u, umxt = 0u;
  for (int j = 0; j < 64; ++j) {
    const unsigned a0 = ui[j << 4];
    const unsigned a1 = ui[1024 + (j << 4)];
    const unsigned a2 = ui[2048 + (j << 4)];
    const unsigned a3 = ui[3072 + (j << 4)];
    umnp = umnp > a0 ? umnp : a0;
    umnt = umnt > a1 ? umnt : a1;
    umxp = umxp > a2 ? umxp : a2;
    umxt = umxt > a3 ? umxt : a3;
  }
  const float mnp = __uint_as_float(~umnp);
  const float mnt = __uint_as_float(~umnt);
  const float mxp = __uint_as_float(umxp);
  const float mxt = __uint_as_float(umxt);
  const float scp = 1.f / (mxp - mnp + 1e-6f);
  const float sct = 1.f / (mxt - mnt + 1e-6f);
  const h8* __restrict__ gp = (const h8*)gmP;
  const h8* __restrict__ gt = (const h8*)gmT;
  float lsum = 0.f;
  const int base = bidx << 9;                      // 512 h8 per block
#pragma unroll
  for (int i = 0; i < 2; ++i) {
    const int idx = base + (i << 8) + threadIdx.x;
    const h8 a = gp[idx];
    const h8 b = gt[idx];
#pragma unroll
    for (int j = 0; j < 8; ++j)
      lsum += fabsf(((float)a[j] - mnp) * scp - ((float)b[j] - mnt) * sct);
  }
  rede[threadIdx.x] = lsum;
  __syncthreads();
  for (int s = 128; s > 0; s >>= 1) {
    if (threadIdx.x < s) rede[threadIdx.x] += rede[threadIdx.x + s];
    __syncthreads();
  }
  if (threadIdx.x == 0)
    atomicAdd(&absB[(bidx & 63) << 3], (double)rede[0]);
}

// ---- L1: xyblur || sobel (bid%3: 0=xy 0..511, 1/2=sobel 0..1023) -----------
__global__ __launch_bounds__(256) void k_fused_a(
    const float* __restrict__ p, const float* __restrict__ t,
    _Float16* __restrict__ A, double* __restrict__ mseB,
    _Float16* __restrict__ gmP, _Float16* __restrict__ gmT,
    unsigned int* __restrict__ ui) {
  __shared__ __align__(16) char pool[50432];  // xy: sr+dr+ring | sobel: sb+rmax
  __shared__ float redshared[256];
  const int bid = blockIdx.x;                 // 0..1535
  const int r3 = bid % 3;
  if (r3 == 0) {
    xyblur_body(p, t, A, mseB, bid / 3, pool, redshared);
  } else {
    const int s = (bid / 3) * 2 + (r3 - 1);               // 0..1023
    sobel_body(p, t, gmP, gmT, ui, s & 7, (s >> 3) & 7, s >> 6,
               pool, redshared);
  }
}

// ---- L2: zblur+ssim || edge_diff (bid%3 interleave) ------------------------
// SSIM from s/d fields: S2=mus^2, D2=mud^2:
//   num = ((S2-D2)/2 + C1) * ((G(ss)-G(dd)-S2+D2)/2 + C2)
//   den = ((S2+D2)/2 + C1) * ((G(ss)+G(dd)-S2-D2)/2 + C2)
__global__ __launch_bounds__(256) void k_zblur_ssim(
    const _Float16* __restrict__ A, double* __restrict__ ssimB,
    const _Float16* __restrict__ gmP, const _Float16* __restrict__ gmT,
    const unsigned int* __restrict__ ui, double* __restrict__ absB) {
  __shared__ h8 s[26][64];      // 26,624 B
  __shared__ float red[256];
  const int tid = threadIdx.x;
  const int bid = blockIdx.x;                 // 0..3071
  const int r3 = bid % 3;
  if (r3 == 2) {
    edge_body(gmP, gmT, ui, absB, bid / 3, red);          // 0..1023
    return;
  }
  const int idx = (bid / 3) * 2 + r3;                     // 0..2047
  const int y = idx & 127;
  const int z0 = ((idx >> 7) & 7) << 4;
  const int batch = idx >> 10;
  const h8* __restrict__ Ah = (const h8*)A;
  const int col8 = (batch << 20) + (y << 6);  // h8 idx of (b,0,y,0)
  for (int l = tid; l < 1664; l += 256) {   // 26 z-rows x 64 h8 (1KB/row)
    const int row = l >> 6, xc = l & 63;
    const int zz = z0 - 5 + row;
    h8 v{};
    if ((unsigned)zz < 128u) v = Ah[col8 + (zz << 13) + xc];
    s[row][xc] = v;
  }
  __syncthreads();
  const int xc = tid & 63;
  const int zg = tid >> 6;                  // 0..3, each handles 4 z's
  float lsum = 0.f;
#pragma unroll
  for (int r = 0; r < 4; ++r) {
    const int zo = (zg << 2) + r;           // 0..15
    h8 m{};
#pragma unroll
    for (int k = 0; k < 11; ++k) {
      const _Float16 w = (_Float16)GW[k];
      m += w * s[zo + k][xc];
    }
#pragma unroll
    for (int j = 0; j < 2; ++j) {           // 2 voxels per h8
      const float mus = (float)m[4 * j + 0];
      const float mud = (float)m[4 * j + 1];
      const float ess = (float)m[4 * j + 2];
      const float edd = (float)m[4 * j + 3];
      const float S2 = mus * mus, D2 = mud * mud;
      const float num = ((S2 - D2) * 0.5f + 1e-4f) *
                        ((ess - edd - S2 + D2) * 0.5f + 9e-4f);
      const float den = ((S2 + D2) * 0.5f + 1e-4f) *
                        ((ess + edd - S2 - D2) * 0.5f + 9e-4f);
      lsum += num / den;
    }
  }
  red[tid] = lsum;
  __syncthreads();
  for (int st = 128; st > 0; st >>= 1) {
    if (tid < st) red[tid] += red[tid + st];
    __syncthreads();
  }
  if (tid == 0) {
    const int bin = idx & 63;
    atomicAdd(&ssimB[bin << 3], (double)red[0]);
  }
}

// ---- final: fold bins, emit the 4 scalars ----------------------------------
__global__ void k_final(const double* __restrict__ dbl, float* __restrict__ out) {
  if (threadIdx.x == 0 && blockIdx.x == 0) {
    double ms = 0.0, ss = 0.0, ab = 0.0;
    for (int j = 0; j < 64; ++j) {
      ms += dbl[j << 3];
      ss += dbl[512 + (j << 3)];
      ab += dbl[1024 + (j << 3)];
    }
    const double N = 4194304.0;
    const double mse   = ms / N;
    const double ssiml = 1.0 - ss / N;
    const double gme   = 1e-6 + ab / N;
    const double total = mse + ssiml + 0.7 * gme;
    out[0] = (float)total;
    out[1] = (float)mse;
    out[2] = (float)ssiml;
    out[3] = (float)gme;
  }
}

extern "C" void kernel_launch(void* const* d_in, const int* in_sizes, int n_in,
                              void* d_out, int out_size, void* d_ws, size_t ws_size,
                              hipStream_t stream) {
  const float* p = (const float*)d_in[0];
  const float* t = (const float*)d_in[1];
  _Float16* A = (_Float16*)d_ws;                    // xy-blurred, 32 MiB
  char* accb = (char*)d_ws + (size_t)20 * VOL;      // @80 MiB
  double* dbl = (double*)accb;
  unsigned int* ui = (unsigned int*)(accb + 12288);
  _Float16* gmP = (_Float16*)((char*)d_ws + 88080384);  // @84 MiB, 16 MiB
  _Float16* gmT = gmP + VOL;
  float* out = (float*)d_out;

  hipMemsetAsync(accb, 0, 28672, stream);           // dbl + ui bins
  k_fused_a<<<1536, 256, 0, stream>>>(p, t, A, dbl, gmP, gmT, ui);
  k_zblur_ssim<<<3072, 256, 0, stream>>>(A, dbl + 512, gmP, gmT, ui, dbl + 1024);
  k_final<<<1, 64, 0, stream>>>(dbl, out);
}

// Round 7
// 147.741 us; speedup vs baseline: 1.0971x; 1.0971x over previous
//
#include <hip/hip_runtime.h>

// ---------------------------------------------------------------------------
// HybridLossDynamic: total = mse + ssim_loss + 0.7*gme over (2,1,128,128,128)
// fp32 volumes. Outputs: [total, mse, ssim_loss, gme].
//
// r21 = r19 structure + ZERO-LDS blury/zblur (register sliding window):
//   * fb/zb were LDS-staging L3-RESIDENT data (A,B = 32MB each, written by
//     the immediately preceding kernel) — staging is pure overhead when the
//     source cache-fits (guide Common-mistake #7). New: each 64-lane group
//     computes 4 consecutive outputs; loads the 14 covering rows ONCE each
//     (contiguous 1KB/wave, L2/L3-hit) and accumulates acc[r] += GW[k-r]*row
//     in registers. Same tap order -> bitwise-identical results. fb: 0 LDS,
//     no barrier; zb: 1KB reduce buffer only. Occupancy VGPR-bound (high).
//   * fa / sobel / edge / final: r19 unchanged.
//
// SSIM chain: 4 fields {s,d,ss,dd}, s=p+t, d=p-t (r15, exact algebra).
// Interleaved [voxel][4 fields] layout (r18).
//
// Measured lessons pinned (DO NOT REVISIT):
//   r7:  y+z fusion -> scattered 16B staging, 200MB HBM. REGRESSED
//   r9/r16: IN-KERNEL FINAL FOLD (threadfence+counter) COSTS >100us.
//   r10/r11: x+y WHOLE-TILE fusion, 63KB/2 blocks/CU. REGRESSED
//   r12: thin per-field slabs -> 5x barrier-latency exposure. REGRESSED
//   r15/r17: SQ_LDS_BANK_CONFLICT = benign 2-way aliasing. Not the lever.
//   r17: sobel 16-slice split: +5MB halo, no gain. 32 slices/block.
//   r19: fa is NOT barrier-bound; 2.5 TB/s is traffic-pattern-inherent.
//   r20: ring x+y fusion REGRESSED: per-kernel LDS (50KB) is charged to
//     EVERY block incl. sobel -> whole-kernel occupancy collapse (38->22%).
//     Role-fusion requires comparable per-role LDS footprints.
//
// ws: A [0,32) MiB | B [32,64) | acc @80 MiB | gm @84 MiB (16 MiB).
// ---------------------------------------------------------------------------

#define VOL 4194304        // 2*128^3 (both batch images)
#define HV  2097152        // one batch image, 128^3

typedef _Float16 h2 __attribute__((ext_vector_type(2)));
typedef _Float16 h4 __attribute__((ext_vector_type(4)));
typedef _Float16 h8 __attribute__((ext_vector_type(8)));

// 11-tap Gaussian, sigma=1.5, normalized:
constexpr float GW[11] = {
    0.00102838f, 0.00759876f, 0.03600077f, 0.10936070f, 0.21300554f,
    0.26601173f,
    0.21300554f, 0.10936070f, 0.03600077f, 0.00759876f, 0.00102838f};

// Interleaved layout: voxel v = b*HV + z*16384 + y*128 + x holds halfs
// [4v..4v+3] = {s,d,ss,dd}.  h8 index: v/2 (2 voxels/h8).
//   batch stride: 1<<20 h8 | z: 1<<13 | y row: 1<<6 (64 h8 = 128 voxels)

// Accumulator region layout (all zero-initialized by one memset):
//   dbl[0..511] mse bins | dbl[512..1023] ssim bins | dbl[1024..1535] abs bins
//   ui[0..1023]  ~min v0 (COMPLEMENTED bits, atomicMax) | ui[1024..2047] ~min
//   v1 | ui[2048..3071] max v0 | ui[3072..4095] max v1

// ---- role: W-blur, 16 rows staged at once, ONE barrier (r19) ---------------
__device__ __forceinline__ void wblur_body(
    const float* __restrict__ p, const float* __restrict__ t,
    _Float16* __restrict__ A, double* __restrict__ mseB, const int bidx,
    char* __restrict__ pool, float* __restrict__ redw) {
  float (* __restrict__ sr)[138] = (float (*)[138])pool;          // 8832 B
  float (* __restrict__ dr)[138] = (float (*)[138])(pool + 8832); // 8832 B
  const int tid = threadIdx.x;
  const int gbase = bidx << 11;              // 16 rows * 128 voxels
  if (tid < 160) {                           // zero the 10 pad cols per row
    const int r = tid / 10, j = tid % 10;
    const int c = (j < 5) ? j : (128 + j);   // {0..4, 133..137}
    sr[r][c] = 0.f; dr[r][c] = 0.f;
  }
  float msel = 0.f;
#pragma unroll
  for (int i = 0; i < 8; ++i) {              // stage 2048 voxels, coalesced
    const int v = (i << 8) + tid;
    const float pv = p[gbase + v];
    const float tv = t[gbase + v];
    const float sv = pv + tv, dv = pv - tv;
    sr[v >> 7][5 + (v & 127)] = sv;
    dr[v >> 7][5 + (v & 127)] = dv;
    msel += dv * dv;
  }
  __syncthreads();                           // THE barrier
  h4* __restrict__ A4 = (h4*)A;
#pragma unroll
  for (int i = 0; i < 8; ++i) {
    const int v = (i << 8) + tid;
    const int row = v >> 7, x = v & 127;
    float as = 0.f, ad = 0.f, ass = 0.f, add_ = 0.f;
#pragma unroll
    for (int k = 0; k < 11; ++k) {
      const float w = GW[k];
      const float a = sr[row][x + k];
      const float b = dr[row][x + k];
      const float wa = w * a;
      const float wb = w * b;
      as += wa; ad += wb;
      ass += wa * a; add_ += wb * b;
    }
    h4 o;
    o[0] = (_Float16)as;  o[1] = (_Float16)ad;
    o[2] = (_Float16)ass; o[3] = (_Float16)add_;
    A4[gbase + v] = o;                       // 8B/lane single stream
  }
  redw[tid] = msel;
  __syncthreads();
  for (int s = 128; s > 0; s >>= 1) {
    if (tid < s) redw[tid] += redw[tid + s];
    __syncthreads();
  }
  if (tid == 0) atomicAdd(&mseB[(bidx & 63) << 3], (double)redw[0]);
}

// ---- role: Sobel via separable s/d/u decomposition, z-streamed (32/block) --
__device__ __forceinline__ void sobel_body(
    const float* __restrict__ p, const float* __restrict__ t,
    _Float16* __restrict__ gmP, _Float16* __restrict__ gmT,
    unsigned int* __restrict__ ui, const int bx, const int by, const int bz,
    char* __restrict__ pool, float* __restrict__ rmin) {
  float* __restrict__ sb   = (float*)pool;           // 1296*4 = 5184 B
  float* __restrict__ rmax = (float*)(pool + 5184);  // 1024 B
  const int tid = threadIdx.x;
  const int tx = tid & 15;
  const int ty = tid >> 4;
  const int x0 = bx << 4;
  const int y0 = by << 4;
  const int vol = bz >> 3;
  const int b   = (bz >> 2) & 1;
  const int z0  = (bz & 3) << 5;             // 32-slice chunks
  const float* __restrict__ img = vol ? t : p;
  _Float16* __restrict__ gm = vol ? gmT : gmP;
  const int vb = b << 21;

  // staging slots: pass1 = tid, pass2 = tid+256 (rows 0..17, stride 24)
  const int ly1 = tid / 24, lx1 = tid % 24;
  const bool v1 = (lx1 < 18);
  int gy1 = y0 - 1 + ly1; gy1 = gy1 < 0 ? 1 : (gy1 > 127 ? 126 : gy1);
  int gx1 = x0 - 1 + lx1; gx1 = gx1 < 0 ? 1 : (gx1 > 127 ? 126 : gx1);
  const int off1 = (gy1 << 7) + gx1;
  const int s2i = tid + 256;
  const int ly2 = s2i / 24, lx2 = s2i % 24;
  const bool v2 = (s2i < 432) && (lx2 < 18);
  int gy2 = y0 - 1 + ly2; gy2 = gy2 < 0 ? 1 : (gy2 > 127 ? 126 : gy2);
  int gx2 = x0 - 1 + lx2; gx2 = gx2 < 0 ? 1 : (gx2 > 127 ? 126 : gx2);
  const int off2 = (gy2 << 7) + gx2;
  const int rb = ty * 24 + tx;
  const int gbase = vb + (z0 << 14) + ((y0 + ty) << 7) + (x0 + tx);

  float Y0[7], Y1[7], Y2[7];
  float rv1 = 0.f, rv2 = 0.f;
  float lmin = 3.4e38f, lmax = 0.f;

#define LOADR(ZS) {                                                         \
    const int zc_ = (ZS) > 127 ? 126 : (ZS);                                \
    const int za_ = vb + (zc_ << 14);                                       \
    if (v1) rv1 = img[za_ + off1];                                          \
    if (v2) rv2 = img[za_ + off2]; }

#define WRITELDS(BOFF) {                                                    \
    if (v1) sb[(BOFF) + tid] = rv1;                                         \
    if (v2) sb[(BOFF) + s2i] = rv2; }

#define COMPY(P) {                                                          \
    const int o_ = (P) * 432 + rb;                                          \
    const float r00 = sb[o_],      r01 = sb[o_ + 1],  r02 = sb[o_ + 2];     \
    const float r10 = sb[o_ + 24], r11 = sb[o_ + 25], r12 = sb[o_ + 26];    \
    const float r20 = sb[o_ + 48], r21 = sb[o_ + 49], r22 = sb[o_ + 50];    \
    const float dx0 = r02 - r00, dx1 = r12 - r10, dx2 = r22 - r20;          \
    const float ux0 = r00 + r01 + r02, ux1 = r10 + r11 + r12,               \
                ux2 = r20 + r21 + r22;                                      \
    const float sx0 = ux0 + r01, sx1 = ux1 + r11, sx2 = ux2 + r21;          \
    Y##P[1] = dx0 + dx1 + dx2;           /* uydx */                         \
    Y##P[0] = Y##P[1] + dx1;             /* sydx */                         \
    Y##P[2] = sx2 - sx0;                 /* dysx */                         \
    Y##P[4] = sx0 + sx1 + sx2;           /* uysx */                         \
    Y##P[3] = Y##P[4] + sx1;             /* sysx */                         \
    Y##P[5] = ux2 - ux0;                 /* dyux */                         \
    Y##P[6] = (ux0 + ux2) + 2.f * ux1; } /* syux */

#define EMIT(I, P0, P1, P2) {                                               \
    const float E_ = Y##P0[0] + Y##P1[0] + Y##P2[0];                        \
    const float g1 = E_ + Y##P1[0];                                         \
    const float tA = Y##P0[1] + Y##P1[1] + Y##P2[1];                        \
    const float A_ = tA + Y##P1[1];                                         \
    const float D_ = Y##P0[2] + Y##P1[2] + Y##P2[2];                        \
    const float g2 = D_ + Y##P1[2];                                         \
    const float g3 = Y##P2[3] - Y##P0[3];                                   \
    const float C_ = Y##P2[4] - Y##P0[4];                                   \
    const float B_ = (Y##P0[5] + Y##P2[5]) + 2.f * Y##P1[5];                \
    const float F_ = Y##P2[6] - Y##P0[6];                                   \
    const float g4 = A_ - B_, g5 = A_ + B_;                                 \
    const float g6 = C_ - D_, g7 = C_ + D_;                                 \
    const float g8 = E_ - F_, g9 = E_ + F_;                                 \
    float ss_ = 9e-6f, t_;                                                  \
    t_ = g1 + 1e-6f; ss_ = fmaf(t_, t_, ss_);                               \
    t_ = g2 + 1e-6f; ss_ = fmaf(t_, t_, ss_);                               \
    t_ = g3 + 1e-6f; ss_ = fmaf(t_, t_, ss_);                               \
    t_ = g4 + 1e-6f; ss_ = fmaf(t_, t_, ss_);                               \
    t_ = g5 + 1e-6f; ss_ = fmaf(t_, t_, ss_);                               \
    t_ = g6 + 1e-6f; ss_ = fmaf(t_, t_, ss_);                               \
    t_ = g7 + 1e-6f; ss_ = fmaf(t_, t_, ss_);                               \
    t_ = g8 + 1e-6f; ss_ = fmaf(t_, t_, ss_);                               \
    t_ = g9 + 1e-6f; ss_ = fmaf(t_, t_, ss_);                               \
    const _Float16 gh = (_Float16)sqrtf(ss_);                               \
    gm[gbase + ((I) << 14)] = gh;                                           \
    const float gq = (float)gh;                                             \
    lmin = fminf(lmin, gq); lmax = fmaxf(lmax, gq); }

#define BODY(I, P0, P1, P2) {                                               \
    WRITELDS((P2) * 432);                                                   \
    LOADR(z0 + (I) + 2);                                                    \
    __syncthreads();                                                        \
    COMPY(P2);                                                              \
    EMIT(I, P0, P1, P2); }

  {
    const int zp = (z0 == 0) ? 1 : (z0 - 1);
    LOADR(zp);  WRITELDS(0);
    LOADR(z0);  WRITELDS(432);
    __syncthreads();
    COMPY(0);
    COMPY(1);
    LOADR(z0 + 1);                           // prime the pipeline
  }
  for (int ii = 0; ii < 30; ii += 3) {
    BODY(ii,     0, 1, 2);
    BODY(ii + 1, 1, 2, 0);
    BODY(ii + 2, 2, 0, 1);
  }
  BODY(30, 0, 1, 2);
  BODY(31, 1, 2, 0);

#undef BODY
#undef EMIT
#undef COMPY
#undef WRITELDS
#undef LOADR

  rmin[tid] = lmin; rmax[tid] = lmax;
  __syncthreads();
  for (int st = 128; st > 0; st >>= 1) {
    if (tid < st) {
      rmin[tid] = fminf(rmin[tid], rmin[tid + st]);
      rmax[tid] = fmaxf(rmax[tid], rmax[tid + st]);
    }
    __syncthreads();
  }
  if (tid == 0) {
    const int bin = (bx + (by << 3) + (bz << 6)) & 63;
    // min stored as max of complemented bits (positive floats bit-ordered):
    atomicMax(&ui[vol * 1024 + (bin << 4)], ~__float_as_uint(rmin[0]));
    atomicMax(&ui[2048 + vol * 1024 + (bin << 4)], __float_as_uint(rmax[0]));
  }
}

// ---- role: mean |norm_p - norm_t| (h8 loads) -------------------------------
__device__ __forceinline__ void edge_body(
    const _Float16* __restrict__ gmP, const _Float16* __restrict__ gmT,
    const unsigned int* __restrict__ ui, double* __restrict__ absB,
    const int bidx, float* __restrict__ rede) {
  unsigned umnp = 0u, umnt = 0u, umxp = 0u, umxt = 0u;
  for (int j = 0; j < 64; ++j) {
    const unsigned a0 = ui[j << 4];
    const unsigned a1 = ui[1024 + (j << 4)];
    const unsigned a2 = ui[2048 + (j << 4)];
    const unsigned a3 = ui[3072 + (j << 4)];
    umnp = umnp > a0 ? umnp : a0;
    umnt = umnt > a1 ? umnt : a1;
    umxp = umxp > a2 ? umxp : a2;
    umxt = umxt > a3 ? umxt : a3;
  }
  const float mnp = __uint_as_float(~umnp);
  const float mnt = __uint_as_float(~umnt);
  const float mxp = __uint_as_float(umxp);
  const float mxt = __uint_as_float(umxt);
  const float scp = 1.f / (mxp - mnp + 1e-6f);
  const float sct = 1.f / (mxt - mnt + 1e-6f);
  const h8* __restrict__ gp = (const h8*)gmP;
  const h8* __restrict__ gt = (const h8*)gmT;
  float lsum = 0.f;
  const int base = bidx << 9;                      // 512 h8 per block
#pragma unroll
  for (int i = 0; i < 2; ++i) {
    const int idx = base + (i << 8) + threadIdx.x;
    const h8 a = gp[idx];
    const h8 b = gt[idx];
#pragma unroll
    for (int j = 0; j < 8; ++j)
      lsum += fabsf(((float)a[j] - mnp) * scp - ((float)b[j] - mnt) * sct);
  }
  rede[threadIdx.x] = lsum;
  __syncthreads();
  for (int s = 128; s > 0; s >>= 1) {
    if (threadIdx.x < s) rede[threadIdx.x] += rede[threadIdx.x + s];
    __syncthreads();
  }
  if (threadIdx.x == 0)
    atomicAdd(&absB[(bidx & 63) << 3], (double)rede[0]);
}

// ---- L1: wblur || sobel (bid%3 in {0,1}=wblur, 2=sobel), pooled LDS --------
__global__ __launch_bounds__(256) void k_fused_a(
    const float* __restrict__ p, const float* __restrict__ t,
    _Float16* __restrict__ A, double* __restrict__ mseB,
    _Float16* __restrict__ gmP, _Float16* __restrict__ gmT,
    unsigned int* __restrict__ ui) {
  __shared__ __align__(16) char pool[17664];  // wblur sr+dr | sobel sb+rmax
  __shared__ float redshared[256];
  const int bid = blockIdx.x;                 // 0..3071
  const int r3 = bid % 3;
  if (r3 < 2) {
    wblur_body(p, t, A, mseB, (bid / 3) * 2 + r3, pool, redshared);
  } else {
    const int s = bid / 3;                                // 0..1023
    sobel_body(p, t, gmP, gmT, ui, s & 7, (s >> 3) & 7, s >> 6,
               pool, redshared);
  }
}

// ---- L2: y-blur, ZERO LDS, register sliding window -------------------------
// Group of 64 lanes (xc) x 4 groups (yg): each group emits 4 consecutive
// y-rows; loads the 14 covering rows once each (1KB/wave, L2/L3-hit).
// acc[r] += GW[k-r]*row[k]: for fixed r, taps accumulate k-r = 0..10
// ascending -> bitwise-identical to the staged version.
__global__ __launch_bounds__(256) void k_fused_b(
    const _Float16* __restrict__ A, _Float16* __restrict__ B) {
  const int idx = blockIdx.x;                 // 0..2047
  const int z = idx & 127;
  const int yseg = (idx >> 7) & 7;
  const int batch = idx >> 10;
  const int tid = threadIdx.x;
  const int xc = tid & 63;
  const int yg = tid >> 6;                    // 0..3
  const h8* __restrict__ Ah = (const h8*)A;
  h8* __restrict__ Bh = (h8*)B;
  const int slice8 = (batch << 20) + (z << 13);   // h8 idx of (b,z,0,0)
  const int ybase = (yseg << 4) + (yg << 2);      // first output row
  h8 acc0{}, acc1{}, acc2{}, acc3{};
#pragma unroll
  for (int k = 0; k < 14; ++k) {
    const int y = ybase - 5 + k;
    h8 rv{};
    if ((unsigned)y < 128u) rv = Ah[slice8 + (y << 6) + xc];
    if (k <= 10)           acc0 += (_Float16)GW[k]      * rv;
    if (k >= 1 && k <= 11) acc1 += (_Float16)GW[k - 1]  * rv;
    if (k >= 2 && k <= 12) acc2 += (_Float16)GW[k - 2]  * rv;
    if (k >= 3)            acc3 += (_Float16)GW[k - 3]  * rv;
  }
  const int wbase = slice8 + (ybase << 6) + xc;
  Bh[wbase]            = acc0;
  Bh[wbase + (1 << 6)] = acc1;
  Bh[wbase + (2 << 6)] = acc2;
  Bh[wbase + (3 << 6)] = acc3;
}

// ---- L3: z-blur+ssim (zero-LDS sliding) || edge_diff (bid%3) ---------------
// SSIM from s/d fields: S2=mus^2, D2=mud^2:
//   num = ((S2-D2)/2 + C1) * ((G(ss)-G(dd)-S2+D2)/2 + C2)
//   den = ((S2+D2)/2 + C1) * ((G(ss)+G(dd)-S2-D2)/2 + C2)
__global__ __launch_bounds__(256) void k_zblur_ssim(
    const _Float16* __restrict__ B, double* __restrict__ ssimB,
    const _Float16* __restrict__ gmP, const _Float16* __restrict__ gmT,
    const unsigned int* __restrict__ ui, double* __restrict__ absB) {
  __shared__ float red[256];
  const int tid = threadIdx.x;
  const int bid = blockIdx.x;                 // 0..3071
  const int r3 = bid % 3;
  if (r3 == 2) {
    edge_body(gmP, gmT, ui, absB, bid / 3, red);          // 0..1023
    return;
  }
  const int idx = (bid / 3) * 2 + r3;                     // 0..2047
  const int y = idx & 127;
  const int zseg = (idx >> 7) & 7;
  const int batch = idx >> 10;
  const int xc = tid & 63;
  const int zg = tid >> 6;                    // 0..3
  const h8* __restrict__ Bh = (const h8*)B;
  const int col8 = (batch << 20) + (y << 6);  // h8 idx of (b,0,y,0)
  const int zbase = (zseg << 4) + (zg << 2);  // first output z
  h8 m0{}, m1{}, m2{}, m3{};
#pragma unroll
  for (int k = 0; k < 14; ++k) {
    const int zz = zbase - 5 + k;
    h8 rv{};
    if ((unsigned)zz < 128u) rv = Bh[col8 + (zz << 13) + xc];
    if (k <= 10)           m0 += (_Float16)GW[k]      * rv;
    if (k >= 1 && k <= 11) m1 += (_Float16)GW[k - 1]  * rv;
    if (k >= 2 && k <= 12) m2 += (_Float16)GW[k - 2]  * rv;
    if (k >= 3)            m3 += (_Float16)GW[k - 3]  * rv;
  }
  float lsum = 0.f;
  h8 mv[4] = {m0, m1, m2, m3};
#pragma unroll
  for (int r = 0; r < 4; ++r) {
#pragma unroll
    for (int j = 0; j < 2; ++j) {             // 2 voxels per h8
      const float mus = (float)mv[r][4 * j + 0];
      const float mud = (float)mv[r][4 * j + 1];
      const float ess = (float)mv[r][4 * j + 2];
      const float edd = (float)mv[r][4 * j + 3];
      const float S2 = mus * mus, D2 = mud * mud;
      const float num = ((S2 - D2) * 0.5f + 1e-4f) *
                        ((ess - edd - S2 + D2) * 0.5f + 9e-4f);
      const float den = ((S2 + D2) * 0.5f + 1e-4f) *
                        ((ess + edd - S2 - D2) * 0.5f + 9e-4f);
      lsum += num / den;
    }
  }
  red[tid] = lsum;
  __syncthreads();
  for (int st = 128; st > 0; st >>= 1) {
    if (tid < st) red[tid] += red[tid + st];
    __syncthreads();
  }
  if (tid == 0) {
    const int bin = idx & 63;
    atomicAdd(&ssimB[bin << 3], (double)red[0]);
  }
}

// ---- final: fold bins, emit the 4 scalars ----------------------------------
__global__ void k_final(const double* __restrict__ dbl, float* __restrict__ out) {
  if (threadIdx.x == 0 && blockIdx.x == 0) {
    double ms = 0.0, ss = 0.0, ab = 0.0;
    for (int j = 0; j < 64; ++j) {
      ms += dbl[j << 3];
      ss += dbl[512 + (j << 3)];
      ab += dbl[1024 + (j << 3)];
    }
    const double N = 4194304.0;
    const double mse   = ms / N;
    const double ssiml = 1.0 - ss / N;
    const double gme   = 1e-6 + ab / N;
    const double total = mse + ssiml + 0.7 * gme;
    out[0] = (float)total;
    out[1] = (float)mse;
    out[2] = (float)ssiml;
    out[3] = (float)gme;
  }
}

extern "C" void kernel_launch(void* const* d_in, const int* in_sizes, int n_in,
                              void* d_out, int out_size, void* d_ws, size_t ws_size,
                              hipStream_t stream) {
  const float* p = (const float*)d_in[0];
  const float* t = (const float*)d_in[1];
  _Float16* A = (_Float16*)d_ws;                    // VOL voxels x 4 halfs = 32 MiB
  _Float16* B = A + (size_t)4 * VOL;                // 32 MiB @ 32 MiB
  char* accb = (char*)d_ws + (size_t)20 * VOL;      // @80 MiB
  double* dbl = (double*)accb;
  unsigned int* ui = (unsigned int*)(accb + 12288);
  _Float16* gmP = (_Float16*)((char*)d_ws + 88080384);  // @84 MiB, 16 MiB
  _Float16* gmT = gmP + VOL;
  float* out = (float*)d_out;

  hipMemsetAsync(accb, 0, 28672, stream);           // dbl + ui bins
  k_fused_a<<<3072, 256, 0, stream>>>(p, t, A, dbl, gmP, gmT, ui);
  k_fused_b<<<2048, 256, 0, stream>>>(A, B);
  k_zblur_ssim<<<3072, 256, 0, stream>>>(B, dbl + 512, gmP, gmT, ui, dbl + 1024);
  k_final<<<1, 64, 0, stream>>>(dbl, out);
}